// Round 4
// baseline (422.403 us; speedup 1.0000x reference)
//
#include <hip/hip_runtime.h>
#include <hip/hip_fp16.h>
#include <stdint.h>

// Two-phase tiny-LSTM (H=1, T=512, B=4096, F=25 split 12+13) + sigmoid head.
// K1 (BW-bound): coalesced float4 loads -> LDS (padded rows) -> per-(chain,t)
//     GEMV with register-resident pre-scaled weights -> fp16 z' to d_ws.
//     z'[t][b][8 halves], pre-scaled by -log2e (i,f,o) / -2log2e (g).
// K2 (latency-bound): 1 lane per (chain,lstm); 512-step serial recurrence,
//     rcp-fused gates, 8-deep register-ring prefetch (z is L3-resident).

#define T_STEPS 512
#define F_IN    25
#define CH      8                    // chains per k1 tile
#define TC      32                   // timesteps per k1 tile
#define NT      (T_STEPS / TC)       // 16 tiles
#define ROWF    (TC * F_IN)          // 800 floats per chain per tile
#define XPAD    8
#define XROW    (ROWF + XPAD)        // 808; 808%32==8 -> compute reads 2-way (free)
#define TILE4   (CH * ROWF / 4)      // 1600 float4 per tile
#define LOG2E   1.44269504088896340736f
#define SC1     (-LOG2E)
#define SC2     (-2.0f * LOG2E)

// ---------------- K1: gate pre-activation compute ----------------
__global__ void __launch_bounds__(256, 2)
k1_gates(const float* __restrict__ x,
         const float* __restrict__ Wih1, const float* __restrict__ b1,
         const float* __restrict__ Wih2, const float* __restrict__ b2,
         uint4* __restrict__ z, int B)
{
  __shared__ __align__(16) float xs[2][CH * XROW];   // 2 x 25.9 KB

  const int tid = threadIdx.x;
  const int c   = tid & 7;           // chain (low bits -> full-line z stores)
  const int tl  = tid >> 3;          // time slot 0..31
  const int b0  = blockIdx.x * CH;
  const int b   = b0 + c;

  // ---- weights into registers, pre-scaled (i,f,o: -log2e ; g: -2log2e) ----
  float w1[48], w2[52], bb[8];
#pragma unroll
  for (int j = 0; j < 4; ++j) {
    const float s = (j == 2) ? SC2 : SC1;
#pragma unroll
    for (int f = 0; f < 12; ++f) w1[j * 12 + f] = Wih1[j * 12 + f] * s;
#pragma unroll
    for (int f = 0; f < 13; ++f) w2[j * 13 + f] = Wih2[j * 13 + f] * s;
    bb[j]     = b1[j] * s;
    bb[4 + j] = b2[j] * s;
  }

  // ---- staging descriptors: 1600 float4/tile, thread takes j = tid + 256r ----
  const float* gsrc[7];   // global float4 base (tile 0); advance by ROWF floats/tile
  int   ldst[7];          // LDS float index
  bool  act[7];
#pragma unroll
  for (int r = 0; r < 7; ++r) {
    const int j = tid + 256 * r;
    act[r] = (j < TILE4);
    const int lc   = j / (ROWF / 4);       // chain 0..7
    const int loff = j - lc * (ROWF / 4);  // float4 within chain row
    gsrc[r] = x + (size_t)(b0 + (act[r] ? lc : 0)) * (T_STEPS * F_IN) + loff * 4;
    ldst[r] = lc * XROW + loff * 4;
  }

  float4 stg[7];
#pragma unroll
  for (int r = 0; r < 7; ++r)
    if (act[r]) stg[r] = *(const float4*)(gsrc[r]);          // tile 0
  // write tile 0 into buf 0 (no barrier needed yet; barrier at loop top)
#pragma unroll
  for (int r = 0; r < 7; ++r)
    if (act[r]) *(float4*)(&xs[0][ldst[r]]) = stg[r];
#pragma unroll
  for (int r = 0; r < 7; ++r)
    if (act[r]) stg[r] = *(const float4*)(gsrc[r] + ROWF);   // tile 1 in flight

  for (int k = 0; k < NT; ++k) {
    __syncthreads();   // prev writes visible; prev reads of other buffer done
    if (k + 1 < NT) {
#pragma unroll
      for (int r = 0; r < 7; ++r)
        if (act[r]) *(float4*)(&xs[(k + 1) & 1][ldst[r]]) = stg[r];
    }

    // ---- compute tile k ----
    const float* __restrict__ xr = &xs[k & 1][c * XROW + tl * F_IN];
    float zz[8];
#pragma unroll
    for (int j = 0; j < 8; ++j) zz[j] = bb[j];
#pragma unroll
    for (int f = 0; f < 12; ++f) {
      const float xv = xr[f];
#pragma unroll
      for (int j = 0; j < 4; ++j) zz[j] = fmaf(w1[j * 12 + f], xv, zz[j]);
    }
#pragma unroll
    for (int f = 0; f < 13; ++f) {
      const float xv = xr[12 + f];
#pragma unroll
      for (int j = 0; j < 4; ++j) zz[4 + j] = fmaf(w2[j * 13 + f], xv, zz[4 + j]);
    }
    const __half2 p0 = __floats2half2_rn(zz[0], zz[1]);
    const __half2 p1 = __floats2half2_rn(zz[2], zz[3]);
    const __half2 p2 = __floats2half2_rn(zz[4], zz[5]);
    const __half2 p3 = __floats2half2_rn(zz[6], zz[7]);
    uint4 q;
    q.x = *(const unsigned int*)&p0;
    q.y = *(const unsigned int*)&p1;
    q.z = *(const unsigned int*)&p2;
    q.w = *(const unsigned int*)&p3;
    z[(size_t)(k * TC + tl) * B + b] = q;    // lanes 0..7 -> one full 128B line

    // ---- prefetch tile k+2 (latency hidden under next tile's compute) ----
    if (k + 2 < NT) {
#pragma unroll
      for (int r = 0; r < 7; ++r)
        if (act[r]) stg[r] = *(const float4*)(gsrc[r] + (size_t)(k + 2) * ROWF);
    }
  }
}

// ---------------- K2: serial recurrence ----------------
__device__ __forceinline__ void lstm_step(const uint2 v,
                                          const float wi, const float wf,
                                          const float wg, const float wo,
                                          float& h, float& cc) {
  const __half2 h01 = *(const __half2*)&v.x;
  const __half2 h23 = *(const __half2*)&v.y;
  const float2 f01 = __half22float2(h01);      // z'_i, z'_f
  const float2 f23 = __half22float2(h23);      // z'_g, z'_o
  const float ei = __builtin_amdgcn_exp2f(fmaf(h, wi, f01.x));  // e^{-pi}
  const float ef = __builtin_amdgcn_exp2f(fmaf(h, wf, f01.y));  // e^{-pf}
  const float eg = __builtin_amdgcn_exp2f(fmaf(h, wg, f23.x));  // e^{-2pg}
  const float eo = __builtin_amdgcn_exp2f(fmaf(h, wo, f23.y));  // e^{-po}
  const float af  = __builtin_amdgcn_rcpf(1.0f + ef);                 // f-gate
  const float rig = __builtin_amdgcn_rcpf((1.0f + ei) * (1.0f + eg));
  const float ig  = (1.0f - eg) * rig;                                // i*tanh(g)
  cc = fmaf(af, cc, ig);
  const float ec  = __builtin_amdgcn_exp2f(cc * SC2);                 // e^{-2c}
  const float roc = __builtin_amdgcn_rcpf((1.0f + eo) * (1.0f + ec));
  h = (1.0f - ec) * roc;                                              // o*tanh(c)
}

__global__ void __launch_bounds__(64, 1)
k2_scan(const uint2* __restrict__ z,
        const float* __restrict__ Whh1, const float* __restrict__ Whh2,
        const float* __restrict__ Wout, const float* __restrict__ bout,
        float* __restrict__ out, int B)
{
  const int l    = threadIdx.x;
  const int bb   = blockIdx.x * 32 + (l >> 1);   // chain
  const int lstm = l & 1;                        // 0 -> LSTM1, 1 -> LSTM2

  const float* wp = lstm ? Whh2 : Whh1;
  const float wi = SC1 * wp[0];
  const float wf = SC1 * wp[1];
  const float wg = SC2 * wp[2];
  const float wo = SC1 * wp[3];

  const uint2* __restrict__ zp = z + (size_t)bb * 2 + lstm;
  const size_t stride = (size_t)B * 2;           // uint2 per timestep

  uint2 rb[8];
#pragma unroll
  for (int j = 0; j < 8; ++j) rb[j] = zp[(size_t)j * stride];

  float h = 0.0f, cc = 0.0f;

  for (int t0 = 0; t0 < T_STEPS - 8; t0 += 8) {
#pragma unroll
    for (int j = 0; j < 8; ++j) {
      const uint2 v = rb[j];
      rb[j] = zp[(size_t)(t0 + j + 8) * stride];   // prefetch 8 ahead
      lstm_step(v, wi, wf, wg, wo, h, cc);
    }
  }
#pragma unroll
  for (int j = 0; j < 8; ++j) lstm_step(rb[j], wi, wf, wg, wo, h, cc);

  // head: out = sigmoid(W_out . [h1,h2] + b_out)
  const float hp = __shfl_xor(h, 1);
  if (lstm == 0) {
    const float p = fmaf(Wout[0], h, fmaf(Wout[1], hp, bout[0]));
    out[bb] = __builtin_amdgcn_rcpf(1.0f + __builtin_amdgcn_exp2f(p * SC1));
  }
}

extern "C" void kernel_launch(void* const* d_in, const int* in_sizes, int n_in,
                              void* d_out, int out_size, void* d_ws, size_t ws_size,
                              hipStream_t stream) {
  const float* x    = (const float*)d_in[0];
  const float* Wih1 = (const float*)d_in[1];
  const float* Whh1 = (const float*)d_in[2];
  const float* b1   = (const float*)d_in[3];
  const float* Wih2 = (const float*)d_in[4];
  const float* Whh2 = (const float*)d_in[5];
  const float* b2   = (const float*)d_in[6];
  const float* Wout = (const float*)d_in[7];
  const float* bout = (const float*)d_in[8];
  float* out = (float*)d_out;

  const int B = in_sizes[0] / (T_STEPS * F_IN);  // 4096

  hipLaunchKernelGGL(k1_gates, dim3(B / CH), dim3(256), 0, stream,
                     x, Wih1, b1, Wih2, b2, (uint4*)d_ws, B);
  hipLaunchKernelGGL(k2_scan, dim3(B / 32), dim3(64), 0, stream,
                     (const uint2*)d_ws, Whh1, Whh2, Wout, bout, out, B);
}

// Round 5
// 361.384 us; speedup vs baseline: 1.1689x; 1.1689x over previous
//
#include <hip/hip_runtime.h>
#include <hip/hip_fp16.h>
#include <stdint.h>

// Two-phase tiny-LSTM (H=1, T=512, B=4096, F=25 split 12+13) + sigmoid head.
// K1 (streaming): 2048 blocks x 1 wave, 2 chains/wave, NO barriers.
//     Triple-buffered LDS tiles staged via global_load_lds dwordx4 (async,
//     coalesced, prefetch distance 2), single static s_waitcnt vmcnt(14)
//     per iteration. GEMV with SGPR-resident pre-scaled weights -> fp16 z'.
//     z'[t][b][8 halves], pre-scaled by -log2e (i,f,o) / -2log2e (g).
// K2 (latency-bound): 1 lane per (chain,lstm); 512-step serial recurrence,
//     rcp-fused gates, 16-deep register-ring prefetch (z is L2/L3-resident).

#define T_STEPS 512
#define F_IN    25
#define TC      32                   // timesteps per tile
#define NT      (T_STEPS / TC)       // 16 tiles
#define CPW     2                    // chains per wave
#define ROWF    (TC * F_IN)          // 800 floats per chain per tile
#define TILEF   (CPW * ROWF)         // 1600 floats per tile (6.4 KB)
#define TILE4   (TILEF / 4)          // 400 float4 per tile
#define LOG2E   1.44269504088896340736f
#define SC1     (-LOG2E)
#define SC2     (-2.0f * LOG2E)

typedef const __attribute__((address_space(1))) void* as1_cvp;
typedef __attribute__((address_space(3)))       void* as3_vp;

__device__ __forceinline__ void gll16(const float* gsrc, const float* ldst) {
  // async global->LDS, 16 B/lane; LDS dst = wave-uniform base + lane*16.
  __builtin_amdgcn_global_load_lds((as1_cvp)(uintptr_t)gsrc,
                                   (as3_vp)(uint32_t)(uintptr_t)ldst, 16, 0, 0);
}

// ---------------- K1: gate pre-activation compute ----------------
__global__ void __launch_bounds__(64)
k1_gates(const float* __restrict__ x,
         const float* __restrict__ Wih1, const float* __restrict__ b1,
         const float* __restrict__ Wih2, const float* __restrict__ b2,
         uint4* __restrict__ z, int B)
{
  __shared__ __align__(16) float xs[3 * TILEF];   // 19.2 KB -> 8 blocks/CU

  const int l  = threadIdx.x;        // lane 0..63
  const int b0 = blockIdx.x * CPW;

  // ---- weights pre-scaled (i,f,o: -log2e ; g: -2log2e); uniform -> SGPRs ----
  float w1[48], w2[52], bb[8];
#pragma unroll
  for (int j = 0; j < 4; ++j) {
    const float s = (j == 2) ? SC2 : SC1;
#pragma unroll
    for (int f = 0; f < 12; ++f) w1[j * 12 + f] = Wih1[j * 12 + f] * s;
#pragma unroll
    for (int f = 0; f < 13; ++f) w2[j * 13 + f] = Wih2[j * 13 + f] * s;
    bb[j]     = b1[j] * s;
    bb[4 + j] = b2[j] * s;
  }

  // ---- GLL descriptors: inst r stages float4 q = l + 64r of the 400-f4 tile ----
  const float* gp[7];
  bool act[7];
#pragma unroll
  for (int r = 0; r < 7; ++r) {
    const int q = l + 64 * r;
    act[r] = (q < TILE4);
    const int chain = (q < 200) ? 0 : 1;          // 200 float4 per chain-row
    const int off4  = q - chain * 200;
    gp[r] = x + (size_t)(b0 + chain) * (T_STEPS * F_IN) + (size_t)off4 * 4;
  }

  // stage tile `tile` into LDS buffer starting at `base` (floats)
  #define STAGE(tile, bufidx)                                            \
    {                                                                    \
      const float* lb = xs + (bufidx) * TILEF;                           \
      _Pragma("unroll")                                                  \
      for (int r = 0; r < 7; ++r)                                        \
        if (act[r]) gll16(gp[r] + (size_t)(tile) * ROWF, lb + r * 256);  \
    }

  const int c  = l >> 5;             // chain 0..1
  const int tl = l & 31;             // time slot 0..31
  const int b  = b0 + c;

  // ---- prologue: tiles 0 and 1 in flight ----
  STAGE(0, 0)
  STAGE(1, 1)

#pragma unroll
  for (int k = 0; k < NT; ++k) {
    // prefetch tile k+2 (clamped at tail so outstanding-count stays static)
    const int tn = (k + 2 < NT) ? (k + 2) : (NT - 1);
    STAGE(tn, (k + 2) % 3)

    // wait: everything older than [GLL(k+1):7][store(k-1):1][GLL(k+2):7]
    // minus 1 -> guarantees GLL(k) fully landed. No barrier; single wave.
    asm volatile("s_waitcnt vmcnt(14)" ::: "memory");

    // ---- compute tile k ----
    const float* __restrict__ xr = xs + (k % 3) * TILEF + c * ROWF + tl * F_IN;
    float zz[8];
#pragma unroll
    for (int j = 0; j < 8; ++j) zz[j] = bb[j];
#pragma unroll
    for (int f = 0; f < 12; ++f) {
      const float xv = xr[f];
#pragma unroll
      for (int j = 0; j < 4; ++j) zz[j] = fmaf(w1[j * 12 + f], xv, zz[j]);
    }
#pragma unroll
    for (int f = 0; f < 13; ++f) {
      const float xv = xr[12 + f];
#pragma unroll
      for (int j = 0; j < 4; ++j) zz[4 + j] = fmaf(w2[j * 13 + f], xv, zz[4 + j]);
    }
    const __half2 p0 = __floats2half2_rn(zz[0], zz[1]);
    const __half2 p1 = __floats2half2_rn(zz[2], zz[3]);
    const __half2 p2 = __floats2half2_rn(zz[4], zz[5]);
    const __half2 p3 = __floats2half2_rn(zz[6], zz[7]);
    uint4 q;
    q.x = *(const unsigned int*)&p0;
    q.y = *(const unsigned int*)&p1;
    q.z = *(const unsigned int*)&p2;
    q.w = *(const unsigned int*)&p3;
    z[(size_t)(k * TC + tl) * B + b] = q;   // c-pairs cover full 32-B sectors
  }
  #undef STAGE
}

// ---------------- K2: serial recurrence ----------------
__device__ __forceinline__ void lstm_step(const uint2 v,
                                          const float wi, const float wf,
                                          const float wg, const float wo,
                                          float& h, float& cc) {
  const __half2 h01 = *(const __half2*)&v.x;
  const __half2 h23 = *(const __half2*)&v.y;
  const float2 f01 = __half22float2(h01);      // z'_i, z'_f
  const float2 f23 = __half22float2(h23);      // z'_g, z'_o
  const float ei = __builtin_amdgcn_exp2f(fmaf(h, wi, f01.x));  // e^{-pi}
  const float ef = __builtin_amdgcn_exp2f(fmaf(h, wf, f01.y));  // e^{-pf}
  const float eg = __builtin_amdgcn_exp2f(fmaf(h, wg, f23.x));  // e^{-2pg}
  const float eo = __builtin_amdgcn_exp2f(fmaf(h, wo, f23.y));  // e^{-po}
  const float af  = __builtin_amdgcn_rcpf(1.0f + ef);                 // f-gate
  const float rig = __builtin_amdgcn_rcpf((1.0f + ei) * (1.0f + eg));
  const float ig  = (1.0f - eg) * rig;                                // i*tanh(g)
  cc = fmaf(af, cc, ig);
  const float ec  = __builtin_amdgcn_exp2f(cc * SC2);                 // e^{-2c}
  const float roc = __builtin_amdgcn_rcpf((1.0f + eo) * (1.0f + ec));
  h = (1.0f - ec) * roc;                                              // o*tanh(c)
}

__global__ void __launch_bounds__(64)
k2_scan(const uint2* __restrict__ z,
        const float* __restrict__ Whh1, const float* __restrict__ Whh2,
        const float* __restrict__ Wout, const float* __restrict__ bout,
        float* __restrict__ out, int B)
{
  const int l    = threadIdx.x;
  const int bb   = blockIdx.x * 32 + (l >> 1);   // chain
  const int lstm = l & 1;                        // 0 -> LSTM1, 1 -> LSTM2

  const float* wp = lstm ? Whh2 : Whh1;
  const float wi = SC1 * wp[0];
  const float wf = SC1 * wp[1];
  const float wg = SC2 * wp[2];
  const float wo = SC1 * wp[3];

  const uint2* __restrict__ zp = z + (size_t)bb * 2 + lstm;
  const size_t stride = (size_t)B * 2;           // uint2 per timestep

  uint2 rb[16];
#pragma unroll
  for (int j = 0; j < 16; ++j) rb[j] = zp[(size_t)j * stride];

  float h = 0.0f, cc = 0.0f;

  for (int t0 = 0; t0 < T_STEPS - 16; t0 += 16) {
#pragma unroll
    for (int j = 0; j < 16; ++j) {
      const uint2 v = rb[j];
      rb[j] = zp[(size_t)(t0 + j + 16) * stride];   // prefetch 16 ahead
      lstm_step(v, wi, wf, wg, wo, h, cc);
    }
  }
#pragma unroll
  for (int j = 0; j < 16; ++j) lstm_step(rb[j], wi, wf, wg, wo, h, cc);

  // head: out = sigmoid(W_out . [h1,h2] + b_out)
  const float hp = __shfl_xor(h, 1);
  if (lstm == 0) {
    const float p = fmaf(Wout[0], h, fmaf(Wout[1], hp, bout[0]));
    out[bb] = __builtin_amdgcn_rcpf(1.0f + __builtin_amdgcn_exp2f(p * SC1));
  }
}

extern "C" void kernel_launch(void* const* d_in, const int* in_sizes, int n_in,
                              void* d_out, int out_size, void* d_ws, size_t ws_size,
                              hipStream_t stream) {
  const float* x    = (const float*)d_in[0];
  const float* Wih1 = (const float*)d_in[1];
  const float* Whh1 = (const float*)d_in[2];
  const float* b1   = (const float*)d_in[3];
  const float* Wih2 = (const float*)d_in[4];
  const float* Whh2 = (const float*)d_in[5];
  const float* b2   = (const float*)d_in[6];
  const float* Wout = (const float*)d_in[7];
  const float* bout = (const float*)d_in[8];
  float* out = (float*)d_out;

  const int B = in_sizes[0] / (T_STEPS * F_IN);  // 4096

  hipLaunchKernelGGL(k1_gates, dim3(B / CPW), dim3(64), 0, stream,
                     x, Wih1, b1, Wih2, b2, (uint4*)d_ws, B);
  hipLaunchKernelGGL(k2_scan, dim3(B / 32), dim3(64), 0, stream,
                     (const uint2*)d_ws, Whh1, Whh2, Wout, bout, out, B);
}